// Round 3
// baseline (10393.299 us; speedup 1.0000x reference)
//
#include <hip/hip_runtime.h>
#include <cstdint>
#include <cstddef>

// Problem dims: B=32, T=2048, D=512, H=512, 4H=2048
#define TT 2048
#define DD 512

// ---------------------------------------------------------------------------
// Phase 1 (chunked): xp = inputs @ Wi + b, layout: xp[tl][gate 4][B 32][col 512]
// fp32 vector GEMM, 128x128x16 tiles, 8x8 per thread.
// ---------------------------------------------------------------------------
#define BM 128
#define BN 128
#define BK 16

__global__ __launch_bounds__(256) void xproj_gemm(
    const float* __restrict__ A,    // [32*2048, 512]
    const float* __restrict__ W,    // [512, 2048]
    const float* __restrict__ bias, // [2048]
    float* __restrict__ C,          // xp chunk
    int t0, int tmask, int tlog)    // T_CH = tmask+1 = 1<<tlog
{
    __shared__ __align__(16) float As[BK][BM + 4];   // [k][m], transposed on load
    __shared__ __align__(16) float Bs[BK][BN + 4];   // [k][n]
    const int tid = threadIdx.x;
    const int nt = blockIdx.x;
    const int mt = blockIdx.y;
    const int m_base = mt * BM;        // chunk-local row (m = bglob*T_CH + tl)
    const int n_base = nt * BN;
    const int ty = tid >> 4;
    const int tx = tid & 15;

    float acc[8][8];
#pragma unroll
    for (int i = 0; i < 8; ++i)
#pragma unroll
        for (int j = 0; j < 8; ++j) acc[i][j] = 0.f;

    for (int k0 = 0; k0 < DD; k0 += BK) {
#pragma unroll
        for (int j = 0; j < 2; ++j) {
            int idx = tid * 2 + j;             // 0..511
            int rowl = idx >> 2, q = idx & 3;  // A: 128 rows x 4 float4
            int rc = m_base + rowl;            // chunk-local row
            int rg = ((rc >> tlog) << 11) + t0 + (rc & tmask);  // global input row
            float4 av = *(const float4*)(A + (size_t)rg * DD + k0 + q * 4);
            As[q * 4 + 0][rowl] = av.x;
            As[q * 4 + 1][rowl] = av.y;
            As[q * 4 + 2][rowl] = av.z;
            As[q * 4 + 3][rowl] = av.w;
            int kr = idx >> 5, nq = idx & 31;  // B: 16 rows x 32 float4
            *(float4*)&Bs[kr][nq * 4] =
                *(const float4*)(W + (size_t)(k0 + kr) * 2048 + n_base + nq * 4);
        }
        __syncthreads();
#pragma unroll
        for (int kk = 0; kk < BK; ++kk) {
            float a[8], bb[8];
            *(float4*)&a[0]  = *(const float4*)&As[kk][ty * 8];
            *(float4*)&a[4]  = *(const float4*)&As[kk][ty * 8 + 4];
            *(float4*)&bb[0] = *(const float4*)&Bs[kk][tx * 8];
            *(float4*)&bb[4] = *(const float4*)&Bs[kk][tx * 8 + 4];
#pragma unroll
            for (int i = 0; i < 8; ++i)
#pragma unroll
                for (int j = 0; j < 8; ++j)
                    acc[i][j] = fmaf(a[i], bb[j], acc[i][j]);
        }
        __syncthreads();
    }
#pragma unroll
    for (int i = 0; i < 8; ++i) {
        int m = m_base + ty * 8 + i;
        int bglob = m >> tlog, tl = m & tmask;
#pragma unroll
        for (int j = 0; j < 8; j += 4) {
            int n = n_base + tx * 8 + j;
            int gate = n >> 9, c = n & 511;    // 8-aligned run never crosses gate
            float4 v;
            v.x = acc[i][j + 0] + bias[n + 0];
            v.y = acc[i][j + 1] + bias[n + 1];
            v.z = acc[i][j + 2] + bias[n + 2];
            v.w = acc[i][j + 3] + bias[n + 3];
            size_t addr = (((size_t)tl * 4 + gate) * 32 + bglob) * 512 + c;
            *(float4*)(C + addr) = v;
        }
    }
}

// ---------------------------------------------------------------------------
// Phase 2: persistent LSTM scan, ZERO intra-block synchronization.
// 16 groups x 16 blocks x 512 threads (1 block/CU). Group g owns batches
// {2g, 2g+1}. Block p owns h-cols [32p, 32p+32). Wave w owns h-cols
// j0+4w..j0+4w+3, ALL 4 gates (16 z-cols), both batches.
// Lane l owns k in {2l,2l+1} + 128q offsets -> h loads are 8 coalesced
// 8-byte agent atomics straight into registers (no LDS anywhere).
// After the butterfly, z_i/z_g/z_f/z_o for one (col,batch) sit on 4 adjacent
// lanes; 3 shfl_xor gathers let lanes l%4==0 (l<32) run the gate math.
// Per-wave flags: producers drain with a per-wave vmcnt(0), store flag;
// consumers poll all 128 group flags (4 cache lines).
// ---------------------------------------------------------------------------
#define NGRP 16
#define BPG  16
#define WPB  8

__device__ __forceinline__ float2 ldg_agent_f2(const float* p) {
    double d = __hip_atomic_load((const double*)p, __ATOMIC_RELAXED,
                                 __HIP_MEMORY_SCOPE_AGENT);
    return __builtin_bit_cast(float2, d);
}

// butterfly reduce step: halve the live value count across lanes differing in bit D
template<int D, int HALF>
__device__ __forceinline__ void rstep(float* p, int lane) {
    const bool hi = (lane & D) != 0;
#pragma unroll
    for (int i = 0; i < HALF; ++i) {
        float send = hi ? p[i] : p[i + HALF];
        float recv = __shfl_xor(send, D, 64);
        p[i] = (hi ? p[i + HALF] : p[i]) + recv;
    }
}

__global__ __launch_bounds__(512) void lstm_scan(
    const float* __restrict__ xp,   // [tl][gate 4][B 32][col 512]
    const float* __restrict__ Wh,   // [512, 2048]
    const float* __restrict__ c0,   // [32, 512]
    const float* __restrict__ h0,   // [32, 512]
    float* __restrict__ out,        // [32, 2048, 512]
    float* hbuf,                    // [2][32][512] ping-pong (persists)
    float* __restrict__ cbuf,       // [32][512] c-state (persists)
    unsigned* __restrict__ flags,   // [16 groups][128]
    int t0, int T_CH, unsigned ep0)
{
    const int tid  = threadIdx.x;
    const int blk  = blockIdx.x;
    const int g    = blk >> 4;      // group 0..15
    const int p    = blk & 15;      // block-in-group
    const int j0   = p * 32;
    const int lane = tid & 63;
    const int w    = tid >> 6;      // wave 0..7

    unsigned* gflags = flags + g * 128;
    const int colb = j0 + 4 * w;    // wave's h-col base

    // ---- Wh fragment -> registers (once). wv[gate*8+q*2+s].{x..w} =
    // Wh[128q + 2*lane + s][gate*512 + colb + (0..3)] ----
    float4 wv[32];
#pragma unroll
    for (int gate = 0; gate < 4; ++gate)
#pragma unroll
        for (int q = 0; q < 4; ++q)
#pragma unroll
            for (int s = 0; s < 2; ++s)
                wv[gate * 8 + q * 2 + s] =
                    *(const float4*)(Wh + (size_t)(128 * q + 2 * lane + s) * 2048
                                     + gate * 512 + colb);

    // active gate lanes: l%4==0, l<32. r = l>>2 -> (cc,b) via bitrev3.
    const int o_ = lane & 3, r_ = lane >> 2;
    const bool act = (o_ == 0) && (lane < 32);
    const int cc = ((r_ & 1) << 1) | ((r_ >> 1) & 1);
    const int bb = (r_ >> 2) & 1;
    const int B  = 2 * g + bb;
    const int col = colb + cc;

    float creg = 0.f;
    float xr[4] = {0.f, 0.f, 0.f, 0.f}, xn[4] = {0.f, 0.f, 0.f, 0.f};
    if (act) {
        size_t o = (size_t)B * 512 + col;
        if (t0 == 0) {
            creg = c0[o];
            __hip_atomic_store(hbuf + o, h0[o], __ATOMIC_RELAXED, __HIP_MEMORY_SCOPE_AGENT);
        } else {
            creg = cbuf[o];   // h already in hbuf[(t0&1)] from prev chunk
        }
#pragma unroll
        for (int gate = 0; gate < 4; ++gate)     // xp prefetch for tl=0
            xr[gate] = xp[((size_t)0 * 4 + gate) * (32 * 512) + (size_t)B * 512 + col];
    }

    // per-wave init flag: drain h0 stores (per-wave vmcnt), then announce
    const unsigned F0 = ep0 + 1;
    asm volatile("s_waitcnt vmcnt(0)" ::: "memory");
    if (lane == 0)
        __hip_atomic_store(gflags + p * 8 + w, F0, __ATOMIC_RELAXED, __HIP_MEMORY_SCOPE_AGENT);

    for (int tl = 0; tl < T_CH; ++tl) {
        const int t = t0 + tl;
        const int cur = t & 1;
        const unsigned e = F0 + (unsigned)tl;

        // ---- poll all 128 producer-wave flags of this group ----
        {
            const unsigned* f1 = gflags + lane;
            const unsigned* f2 = gflags + 64 + lane;
            while (true) {
                unsigned a  = __hip_atomic_load(f1, __ATOMIC_RELAXED, __HIP_MEMORY_SCOPE_AGENT);
                unsigned b2 = __hip_atomic_load(f2, __ATOMIC_RELAXED, __HIP_MEMORY_SCOPE_AGENT);
                if (__all((a >= e) && (b2 >= e))) break;
                __builtin_amdgcn_s_sleep(1);
            }
        }

        // ---- h -> registers: 8 coalesced 8B agent loads (2 batches x 4 quarters) ----
        const float* hp = hbuf + (size_t)cur * (32 * 512) + (size_t)(2 * g) * 512 + 2 * lane;
        float2 hd[2][4];
#pragma unroll
        for (int b = 0; b < 2; ++b)
#pragma unroll
            for (int q = 0; q < 4; ++q)
                hd[b][q] = ldg_agent_f2(hp + b * 512 + q * 128);

        // ---- dot: pp[gate*8 + cc*2 + b], k = 128q + 2l + s ----
        float pp[32];
#pragma unroll
        for (int i = 0; i < 32; ++i) pp[i] = 0.f;
#pragma unroll
        for (int b = 0; b < 2; ++b)
#pragma unroll
            for (int q = 0; q < 4; ++q) {
                const float2 h2 = hd[b][q];
#pragma unroll
                for (int s = 0; s < 2; ++s) {
                    const float hs = s ? h2.y : h2.x;
#pragma unroll
                    for (int gate = 0; gate < 4; ++gate) {
                        const float4 wq = wv[gate * 8 + q * 2 + s];
                        pp[gate * 8 + 0 + b] = fmaf(hs, wq.x, pp[gate * 8 + 0 + b]);
                        pp[gate * 8 + 2 + b] = fmaf(hs, wq.y, pp[gate * 8 + 2 + b]);
                        pp[gate * 8 + 4 + b] = fmaf(hs, wq.z, pp[gate * 8 + 4 + b]);
                        pp[gate * 8 + 6 + b] = fmaf(hs, wq.w, pp[gate * 8 + 6 + b]);
                    }
                }
            }

        // ---- butterfly: lane ends with total for idx = bitrev5(lane&31) ----
        rstep<1, 16>(pp, lane);
        rstep<2, 8>(pp, lane);
        rstep<4, 4>(pp, lane);
        rstep<8, 2>(pp, lane);
        rstep<16, 1>(pp, lane);
        float v0 = pp[0] + __shfl_xor(pp[0], 32, 64);
        // idx = gate*8 + cc*2 + b; lane 4r+o holds gate (2*o0+o1) of (cc,b)=bitrev3(r)
        float zg = __shfl_xor(v0, 1, 64);   // gate 'g' (o=1)
        float zf = __shfl_xor(v0, 2, 64);   // gate 'f' (o=2)
        float zo = __shfl_xor(v0, 3, 64);   // gate 'o' (o=3)

        float hn = 0.f;
        if (act) {
            float z0 = xr[0] + v0;   // i
            float z1 = xr[1] + zf;   // f
            float z2 = xr[2] + zg;   // g
            float z3 = xr[3] + zo;   // o
            float si = 1.f / (1.f + expf(-z0));
            float sf = 1.f / (1.f + expf(-z1));
            float tg = tanhf(z2);
            float so = 1.f / (1.f + expf(-z3));
            float cn = sf * creg + si * tg;
            hn = so * tanhf(cn);
            creg = cn;
            __hip_atomic_store(
                hbuf + (size_t)(cur ^ 1) * (32 * 512) + (size_t)B * 512 + col,
                hn, __ATOMIC_RELAXED, __HIP_MEMORY_SCOPE_AGENT);
        }
        // per-wave drain: h stores at coherence point before flag
        asm volatile("s_waitcnt vmcnt(0)" ::: "memory");
        if (lane == 0)
            __hip_atomic_store(gflags + p * 8 + w, e + 1, __ATOMIC_RELAXED, __HIP_MEMORY_SCOPE_AGENT);
        if (act) {
            // out store + next-step xp prefetch in the propagation window
            out[((size_t)B * TT + t) * 512 + col] = hn;
            if (tl + 1 < T_CH) {
#pragma unroll
                for (int gate = 0; gate < 4; ++gate)
                    xn[gate] = xp[(((size_t)(tl + 1) * 4 + gate) * 32 + B) * 512 + col];
            }
#pragma unroll
            for (int gate = 0; gate < 4; ++gate) xr[gate] = xn[gate];
        }
    }

    // persist c for next chunk launch (plain; kernel-boundary coherence)
    if (act) cbuf[(size_t)B * 512 + col] = creg;
}

// ---------------------------------------------------------------------------
extern "C" void kernel_launch(void* const* d_in, const int* in_sizes, int n_in,
                              void* d_out, int out_size, void* d_ws, size_t ws_size,
                              hipStream_t stream) {
    const float* inputs = (const float*)d_in[0];
    // d_in[1] = input_paddings: unused (reference discards it)
    const float* c0   = (const float*)d_in[2];
    const float* h0   = (const float*)d_in[3];
    const float* Wi   = (const float*)d_in[4];
    const float* Wh   = (const float*)d_in[5];
    const float* bias = (const float*)d_in[6];
    float* out = (float*)d_out;

    // ws layout (floats): [hbuf 32768][cbuf 16384][flags region][xp]
    float* ws_f = (float*)d_ws;
    float* hbuf = ws_f;
    float* cbuf = ws_f + 32768;
    unsigned* flags = (unsigned*)(ws_f + 49152);
    float* xp = ws_f + 49152 + 16384 + 128;          // 65664 (16B aligned)
    const size_t extras_bytes = 65664 * sizeof(float);

    // pick largest T-chunk (pow2, <=256) whose xp slab fits in ws
    int T_CH = 256;
    while (T_CH > 32 &&
           extras_bytes + (size_t)T_CH * 65536 * sizeof(float) > ws_size)
        T_CH >>= 1;
    int tlog = 31 - __builtin_clz((unsigned)T_CH);

    // flags: 16 groups x 128 per-wave epochs; monotone from ep0+1
    hipMemsetAsync(flags, 0, NGRP * 128 * sizeof(unsigned), stream);

    for (int t0 = 0; t0 < TT; t0 += T_CH) {
        dim3 g1(2048 / BN, (32 * T_CH) / BM);
        xproj_gemm<<<g1, 256, 0, stream>>>(inputs, Wi, bias, xp, t0, T_CH - 1, tlog);

        const float* xp_c = xp;
        int t0_arg = t0, tch_arg = T_CH;
        unsigned ep0 = (unsigned)(t0 / T_CH) * (unsigned)(T_CH + 1);
        void* args[] = { (void*)&xp_c, (void*)&Wh, (void*)&c0, (void*)&h0,
                         (void*)&out, (void*)&hbuf, (void*)&cbuf,
                         (void*)&flags,
                         (void*)&t0_arg, (void*)&tch_arg, (void*)&ep0 };
        hipLaunchCooperativeKernel((const void*)lstm_scan, dim3(NGRP * BPG), dim3(512),
                                   args, 0, stream);
    }
}